// Round 1
// baseline (417.454 us; speedup 1.0000x reference)
//
#include <hip/hip_runtime.h>

// FlashAttentionBlock: B=2, S=4096, D=1024, TILE=128 (per-tile softmax)
// Pipeline: cast->bf16; Q/K/V proj GEMMs; V transpose; QK^T+softmax GEMM;
// PV GEMM; output proj GEMM. All GEMMs are B^T layout, 128x128 tile, BK=32,
// mfma_f32_16x16x32_bf16, global_load_lds width-16 staging (m97 structure).

#define D_ 1024
#define S_ 4096
#define B_ 2

typedef unsigned short u16;
typedef float f32x4 __attribute__((ext_vector_type(4)));
typedef float float4v __attribute__((ext_vector_type(4)));
typedef __bf16 bf16x8 __attribute__((ext_vector_type(8)));
typedef unsigned short us8 __attribute__((ext_vector_type(8)));

static __device__ __forceinline__ u16 f2bf(float f) {
    unsigned int u = __builtin_bit_cast(unsigned int, f);
    u += 0x7FFFu + ((u >> 16) & 1u);   // RNE
    return (u16)(u >> 16);
}

static __device__ __forceinline__ void gld16(const u16* g, u16* l) {
    __builtin_amdgcn_global_load_lds(
        (const __attribute__((address_space(1))) void*)g,
        (__attribute__((address_space(3))) void*)l, 16, 0, 0);
}

// ---------------- cast kernels ----------------
__global__ void cast_kernel(const float* __restrict__ in, u16* __restrict__ out, int n8) {
    int i = blockIdx.x * blockDim.x + threadIdx.x;
    int stride = gridDim.x * blockDim.x;
    for (; i < n8; i += stride) {
        const float4v* p = (const float4v*)in + 2 * (size_t)i;
        float4v a = p[0], b = p[1];
        us8 o;
        o[0] = f2bf(a[0]); o[1] = f2bf(a[1]); o[2] = f2bf(a[2]); o[3] = f2bf(a[3]);
        o[4] = f2bf(b[0]); o[5] = f2bf(b[1]); o[6] = f2bf(b[2]); o[7] = f2bf(b[3]);
        *((us8*)out + i) = o;
    }
}

__global__ void cast4_kernel(const float* __restrict__ w0, const float* __restrict__ w1,
                             const float* __restrict__ w2, const float* __restrict__ w3,
                             u16* __restrict__ out, int n8per) {
    const float* srcs[4] = {w0, w1, w2, w3};
    const float* in = srcs[blockIdx.y];
    u16* o = out + (size_t)blockIdx.y * (size_t)n8per * 8;
    int i = blockIdx.x * blockDim.x + threadIdx.x;
    int stride = gridDim.x * blockDim.x;
    for (; i < n8per; i += stride) {
        const float4v* p = (const float4v*)in + 2 * (size_t)i;
        float4v a = p[0], b = p[1];
        us8 v;
        v[0] = f2bf(a[0]); v[1] = f2bf(a[1]); v[2] = f2bf(a[2]); v[3] = f2bf(a[3]);
        v[4] = f2bf(b[0]); v[5] = f2bf(b[1]); v[6] = f2bf(b[2]); v[7] = f2bf(b[3]);
        *((us8*)o + i) = v;
    }
}

// ---------------- bf16 transpose (V -> V^T per batch) ----------------
__global__ void transpose_v(const u16* __restrict__ V, u16* __restrict__ Vt) {
    __shared__ u16 t[64][72];   // +8 pad, keeps 16B alignment (144B row)
    const int tid = threadIdx.x;
    const int d0 = blockIdx.x * 64;
    const int s0 = blockIdx.y * 64;
    const u16* Vb = V + (size_t)blockIdx.z * ((size_t)S_ * D_);
    u16* Vtb = Vt + (size_t)blockIdx.z * ((size_t)D_ * S_);
#pragma unroll
    for (int it = 0; it < 2; it++) {
        int idx = it * 256 + tid;
        int row = idx >> 3;       // s index 0..63
        int ch = idx & 7;         // 8-elem chunk along d
        us8 v = *(const us8*)&Vb[(size_t)(s0 + row) * D_ + d0 + ch * 8];
        *(us8*)&t[row][ch * 8] = v;
    }
    __syncthreads();
#pragma unroll
    for (int it = 0; it < 2; it++) {
        int idx = it * 256 + tid;
        int jj = idx >> 3;        // d index 0..63
        int ch = idx & 7;         // 8-elem chunk along s
        us8 v;
#pragma unroll
        for (int e = 0; e < 8; e++) v[e] = t[ch * 8 + e][jj];
        *(us8*)&Vtb[(size_t)(d0 + jj) * S_ + s0 + ch * 8] = v;
    }
}

// ---------------- generic B^T GEMM: C = A[M,K] * B[N,K]^T ----------------
// EPI 0: bf16 out + f32 bias; EPI 1: bf16 out * scale; EPI 2: f32 out + bias
template <int EPI>
__global__ __launch_bounds__(256, 2) void gemm_bt(
    const u16* __restrict__ A, const u16* __restrict__ B, void* __restrict__ Cv,
    const float* __restrict__ bias, int K, int lda, int ldb, int ldc,
    long sA, long sB, long sC, float scale)
{
    __shared__ u16 lA[128 * 32];
    __shared__ u16 lB[128 * 32];
    const int tid = threadIdx.x;
    const int lane = tid & 63;
    const int wid = tid >> 6;
    const int wr = wid >> 1, wc = wid & 1;
    const int z = blockIdx.z;
    A += (size_t)z * sA;
    B += (size_t)z * sB;
    const int m0 = blockIdx.y * 128;
    const int n0 = blockIdx.x * 128;

    f32x4 acc[4][4];
#pragma unroll
    for (int i = 0; i < 4; i++)
#pragma unroll
        for (int j = 0; j < 4; j++)
#pragma unroll
            for (int r = 0; r < 4; r++) acc[i][j][r] = 0.0f;

    const int ar = lane & 15;
    const int ak = (lane >> 4) * 8;
    const int srow = tid >> 2;        // 0..63
    const int scol = (tid & 3) * 8;   // 0,8,16,24
    const u16* ga = A + (size_t)(m0 + srow) * lda + scol;
    const u16* gb = B + (size_t)(n0 + srow) * ldb + scol;

    for (int k0 = 0; k0 < K; k0 += 32) {
        gld16(ga + k0, &lA[tid * 8]);
        gld16(ga + k0 + (size_t)64 * lda, &lA[2048 + tid * 8]);
        gld16(gb + k0, &lB[tid * 8]);
        gld16(gb + k0 + (size_t)64 * ldb, &lB[2048 + tid * 8]);
        __syncthreads();   // compiler drains vmcnt(0) before s_barrier
        bf16x8 afr[4], bfr[4];
#pragma unroll
        for (int mi = 0; mi < 4; mi++)
            afr[mi] = *(const bf16x8*)&lA[(wr * 64 + mi * 16 + ar) * 32 + ak];
#pragma unroll
        for (int ni = 0; ni < 4; ni++)
            bfr[ni] = *(const bf16x8*)&lB[(wc * 64 + ni * 16 + ar) * 32 + ak];
#pragma unroll
        for (int mi = 0; mi < 4; mi++)
#pragma unroll
            for (int ni = 0; ni < 4; ni++)
                acc[mi][ni] = __builtin_amdgcn_mfma_f32_16x16x32_bf16(
                    afr[mi], bfr[ni], acc[mi][ni], 0, 0, 0);
        __syncthreads();
    }

    const int rr = (lane >> 4) * 4;   // C/D: col = lane&15, row = (lane>>4)*4 + reg
    const int cc = lane & 15;
#pragma unroll
    for (int mi = 0; mi < 4; mi++) {
#pragma unroll
        for (int ni = 0; ni < 4; ni++) {
            const int col = n0 + wc * 64 + ni * 16 + cc;
            const int rowb = m0 + wr * 64 + mi * 16 + rr;
            if constexpr (EPI == 0) {
                u16* C = (u16*)Cv + (size_t)z * sC;
                const float bv = bias[col];
#pragma unroll
                for (int r = 0; r < 4; r++)
                    C[(size_t)(rowb + r) * ldc + col] = f2bf(acc[mi][ni][r] + bv);
            } else if constexpr (EPI == 1) {
                u16* C = (u16*)Cv + (size_t)z * sC;
#pragma unroll
                for (int r = 0; r < 4; r++)
                    C[(size_t)(rowb + r) * ldc + col] = f2bf(acc[mi][ni][r] * scale);
            } else {
                float* C = (float*)Cv + (size_t)z * sC;
                const float bv = bias[col];
#pragma unroll
                for (int r = 0; r < 4; r++)
                    C[(size_t)(rowb + r) * ldc + col] = acc[mi][ni][r] + bv;
            }
        }
    }
}

// ---------------- scores GEMM + fused per-128-tile softmax ----------------
// Wave layout 4x1: wave w owns rows w*32..w*32+31, all 128 cols -> softmax
// group (128 keys) lives inside one wave: reduce over 8 in-reg ni +
// shfl_xor {1,2,4,8} (lanes sharing lane>>4 hold the same row).
__global__ __launch_bounds__(256, 2) void gemm_scores(
    const u16* __restrict__ Q, const u16* __restrict__ Kmat, u16* __restrict__ W,
    int K, int lda, int ldb, int ldc, long sQ, long sK, long sW)
{
    __shared__ u16 lA[128 * 32];
    __shared__ u16 lB[128 * 32];
    const int tid = threadIdx.x;
    const int lane = tid & 63;
    const int wid = tid >> 6;
    const int z = blockIdx.z;
    const u16* Aq = Q + (size_t)z * sQ;
    const u16* Bk = Kmat + (size_t)z * sK;
    const int m0 = blockIdx.y * 128;
    const int n0 = blockIdx.x * 128;

    f32x4 acc[2][8];
#pragma unroll
    for (int i = 0; i < 2; i++)
#pragma unroll
        for (int j = 0; j < 8; j++)
#pragma unroll
            for (int r = 0; r < 4; r++) acc[i][j][r] = 0.0f;

    const int ar = lane & 15;
    const int ak = (lane >> 4) * 8;
    const int srow = tid >> 2;
    const int scol = (tid & 3) * 8;
    const u16* ga = Aq + (size_t)(m0 + srow) * lda + scol;
    const u16* gb = Bk + (size_t)(n0 + srow) * ldb + scol;

    for (int k0 = 0; k0 < K; k0 += 32) {
        gld16(ga + k0, &lA[tid * 8]);
        gld16(ga + k0 + (size_t)64 * lda, &lA[2048 + tid * 8]);
        gld16(gb + k0, &lB[tid * 8]);
        gld16(gb + k0 + (size_t)64 * ldb, &lB[2048 + tid * 8]);
        __syncthreads();
        bf16x8 afr[2], bfr[8];
#pragma unroll
        for (int mi = 0; mi < 2; mi++)
            afr[mi] = *(const bf16x8*)&lA[(wid * 32 + mi * 16 + ar) * 32 + ak];
#pragma unroll
        for (int ni = 0; ni < 8; ni++)
            bfr[ni] = *(const bf16x8*)&lB[(ni * 16 + ar) * 32 + ak];
#pragma unroll
        for (int mi = 0; mi < 2; mi++)
#pragma unroll
            for (int ni = 0; ni < 8; ni++)
                acc[mi][ni] = __builtin_amdgcn_mfma_f32_16x16x32_bf16(
                    afr[mi], bfr[ni], acc[mi][ni], 0, 0, 0);
        __syncthreads();
    }

    // fused softmax over the 128 columns (one KV tile), then bf16 store
    const float SL = 0.03125f * 1.44269504088896341f;  // scale * log2(e)
    const int g4 = (lane >> 4) * 4;
    const int cc = lane & 15;
    u16* Wp = W + (size_t)z * sW;
#pragma unroll
    for (int mi = 0; mi < 2; mi++) {
#pragma unroll
        for (int r = 0; r < 4; r++) {
            float m = acc[mi][0][r];
#pragma unroll
            for (int ni = 1; ni < 8; ni++) m = fmaxf(m, acc[mi][ni][r]);
            m = fmaxf(m, __shfl_xor(m, 1));
            m = fmaxf(m, __shfl_xor(m, 2));
            m = fmaxf(m, __shfl_xor(m, 4));
            m = fmaxf(m, __shfl_xor(m, 8));
            float e[8], s = 0.0f;
#pragma unroll
            for (int ni = 0; ni < 8; ni++) {
                e[ni] = exp2f((acc[mi][ni][r] - m) * SL);
                s += e[ni];
            }
            s += __shfl_xor(s, 1);
            s += __shfl_xor(s, 2);
            s += __shfl_xor(s, 4);
            s += __shfl_xor(s, 8);
            const float inv = 1.0f / s;
            const int row = m0 + wid * 32 + mi * 16 + g4 + r;
#pragma unroll
            for (int ni = 0; ni < 8; ni++)
                Wp[(size_t)row * ldc + n0 + ni * 16 + cc] = f2bf(e[ni] * inv);
        }
    }
}

// ---------------- launch ----------------
extern "C" void kernel_launch(void* const* d_in, const int* in_sizes, int n_in,
                              void* d_out, int out_size, void* d_ws, size_t ws_size,
                              hipStream_t stream)
{
    const float* X  = (const float*)d_in[0];
    const float* Wq = (const float*)d_in[1];
    const float* bq = (const float*)d_in[2];
    const float* Wk = (const float*)d_in[3];
    const float* bk = (const float*)d_in[4];
    const float* Wv = (const float*)d_in[5];
    const float* bv = (const float*)d_in[6];
    const float* Wo = (const float*)d_in[7];
    const float* bo = (const float*)d_in[8];
    float* OUT = (float*)d_out;

    u16* ws = (u16*)d_ws;
    const size_t NTOK = (size_t)B_ * S_;   // 8192
    const size_t XSZ = NTOK * D_;          // 8,388,608 elems
    u16* Xb  = ws;                         // [8192,1024] bf16 (reused as Ob later)
    u16* Qb  = Xb + XSZ;
    u16* Kb  = Qb + XSZ;
    u16* Vb  = Kb + XSZ;
    u16* Vt  = Vb + XSZ;                   // [B][1024][4096]
    u16* Wqb = Vt + XSZ;
    u16* Wkb = Wqb + (size_t)D_ * D_;
    u16* Wvb = Wkb + (size_t)D_ * D_;
    u16* Wob = Wvb + (size_t)D_ * D_;
    u16* Wsm = Wob + (size_t)D_ * D_;      // [B][4096][4096] softmaxed weights
    u16* Ob  = Xb;                         // alias: X dead after projections

    cast_kernel<<<dim3(2048), dim3(256), 0, stream>>>(X, Xb, (int)(XSZ / 8));
    cast4_kernel<<<dim3(512, 4), dim3(256), 0, stream>>>(Wq, Wk, Wv, Wo, Wqb,
                                                         (int)((size_t)D_ * D_ / 8));

    dim3 gp(D_ / 128, NTOK / 128, 1);      // (8, 64)
    gemm_bt<0><<<gp, 256, 0, stream>>>(Xb, Wqb, Qb, bq, D_, D_, D_, D_, 0, 0, 0, 1.0f);
    gemm_bt<0><<<gp, 256, 0, stream>>>(Xb, Wkb, Kb, bk, D_, D_, D_, D_, 0, 0, 0, 1.0f);
    gemm_bt<0><<<gp, 256, 0, stream>>>(Xb, Wvb, Vb, bv, D_, D_, D_, D_, 0, 0, 0, 1.0f);

    transpose_v<<<dim3(D_ / 64, S_ / 64, B_), 256, 0, stream>>>(Vb, Vt);

    gemm_scores<<<dim3(S_ / 128, S_ / 128, B_), 256, 0, stream>>>(
        Qb, Kb, Wsm, D_, D_, D_, S_, (long)S_ * D_, (long)S_ * D_, (long)S_ * S_);

    gemm_bt<1><<<dim3(D_ / 128, S_ / 128, B_), 256, 0, stream>>>(
        Wsm, Vt, Ob, nullptr, S_, S_, S_, D_,
        (long)S_ * S_, (long)D_ * S_, (long)S_ * D_, 1.0f / (32.0f + 1e-6f));

    gemm_bt<2><<<dim3(D_ / 128, NTOK / 128, 1), 256, 0, stream>>>(
        Ob, Wob, OUT, bo, D_, D_, D_, D_, 0, 0, 0, 1.0f);
}

// Round 2
// 405.135 us; speedup vs baseline: 1.0304x; 1.0304x over previous
//
#include <hip/hip_runtime.h>

// FlashAttentionBlock: B=2, S=4096, D=1024, TILE=128 (per-tile softmax)
// R2: fused QKV projection (N=3072, A read once) + XCD-chunked block swizzle
// on all GEMMs (slab of gy/8 M-rows per XCD, y-fastest within slab -> A-panels
// stay resident in the XCD-private 4MB L2 while B streams once).

#define D_ 1024
#define S_ 4096
#define B_ 2

typedef unsigned short u16;
typedef float f32x4 __attribute__((ext_vector_type(4)));
typedef float float4v __attribute__((ext_vector_type(4)));
typedef __bf16 bf16x8 __attribute__((ext_vector_type(8)));
typedef unsigned short us8 __attribute__((ext_vector_type(8)));

static __device__ __forceinline__ u16 f2bf(float f) {
    unsigned int u = __builtin_bit_cast(unsigned int, f);
    u += 0x7FFFu + ((u >> 16) & 1u);   // RNE
    return (u16)(u >> 16);
}

static __device__ __forceinline__ void gld16(const u16* g, u16* l) {
    __builtin_amdgcn_global_load_lds(
        (const __attribute__((address_space(1))) void*)g,
        (__attribute__((address_space(3))) void*)l, 16, 0, 0);
}

// XCD-chunked swizzle: hw linear id round-robins XCDs (id%8). Give XCD c the
// M-row slab [c*ry, (c+1)*ry), y-fastest within the slab so consecutive
// same-XCD blocks share a B-panel and the slab's ry A-panels stay L2-resident.
// Requires gridDim.y % 8 == 0 (all our grids satisfy this). Bijective.
static __device__ __forceinline__ void xcd_map(int& bx, int& by) {
    const int gx = gridDim.x, gy = gridDim.y;
    int lin = blockIdx.x + blockIdx.y * gx;
    int ry = gy >> 3;
    int idx = lin >> 3;
    int q = idx / ry;
    bx = q;
    by = (lin & 7) * ry + (idx - q * ry);
}

// ---------------- cast kernels ----------------
__global__ void cast_kernel(const float* __restrict__ in, u16* __restrict__ out, int n8) {
    int i = blockIdx.x * blockDim.x + threadIdx.x;
    int stride = gridDim.x * blockDim.x;
    for (; i < n8; i += stride) {
        const float4v* p = (const float4v*)in + 2 * (size_t)i;
        float4v a = p[0], b = p[1];
        us8 o;
        o[0] = f2bf(a[0]); o[1] = f2bf(a[1]); o[2] = f2bf(a[2]); o[3] = f2bf(a[3]);
        o[4] = f2bf(b[0]); o[5] = f2bf(b[1]); o[6] = f2bf(b[2]); o[7] = f2bf(b[3]);
        *((us8*)out + i) = o;
    }
}

__global__ void cast4_kernel(const float* __restrict__ w0, const float* __restrict__ w1,
                             const float* __restrict__ w2, const float* __restrict__ w3,
                             u16* __restrict__ out, int n8per) {
    const float* srcs[4] = {w0, w1, w2, w3};
    const float* in = srcs[blockIdx.y];
    u16* o = out + (size_t)blockIdx.y * (size_t)n8per * 8;
    int i = blockIdx.x * blockDim.x + threadIdx.x;
    int stride = gridDim.x * blockDim.x;
    for (; i < n8per; i += stride) {
        const float4v* p = (const float4v*)in + 2 * (size_t)i;
        float4v a = p[0], b = p[1];
        us8 v;
        v[0] = f2bf(a[0]); v[1] = f2bf(a[1]); v[2] = f2bf(a[2]); v[3] = f2bf(a[3]);
        v[4] = f2bf(b[0]); v[5] = f2bf(b[1]); v[6] = f2bf(b[2]); v[7] = f2bf(b[3]);
        *((us8*)o + i) = v;
    }
}

__global__ void concat_bias(const float* __restrict__ b0, const float* __restrict__ b1,
                            const float* __restrict__ b2, float* __restrict__ out) {
    int i = blockIdx.x * 256 + threadIdx.x;   // 3072 threads
    const float* s = (i < 1024) ? b0 : ((i < 2048) ? b1 : b2);
    out[i] = s[i & 1023];
}

// ---------------- bf16 transpose (V -> V^T per batch), V row stride ldv ----
__global__ void transpose_v(const u16* __restrict__ V, u16* __restrict__ Vt, int ldv) {
    __shared__ u16 t[64][72];   // +8 pad
    const int tid = threadIdx.x;
    const int d0 = blockIdx.x * 64;
    const int s0 = blockIdx.y * 64;
    const u16* Vb = V + (size_t)blockIdx.z * ((size_t)S_ * ldv);
    u16* Vtb = Vt + (size_t)blockIdx.z * ((size_t)D_ * S_);
#pragma unroll
    for (int it = 0; it < 2; it++) {
        int idx = it * 256 + tid;
        int row = idx >> 3;
        int ch = idx & 7;
        us8 v = *(const us8*)&Vb[(size_t)(s0 + row) * ldv + d0 + ch * 8];
        *(us8*)&t[row][ch * 8] = v;
    }
    __syncthreads();
#pragma unroll
    for (int it = 0; it < 2; it++) {
        int idx = it * 256 + tid;
        int jj = idx >> 3;
        int ch = idx & 7;
        us8 v;
#pragma unroll
        for (int e = 0; e < 8; e++) v[e] = t[ch * 8 + e][jj];
        *(us8*)&Vtb[(size_t)(d0 + jj) * S_ + s0 + ch * 8] = v;
    }
}

// ---------------- generic B^T GEMM: C = A[M,K] * B[N,K]^T ----------------
// EPI 0: bf16 out + f32 bias; EPI 1: bf16 out * scale; EPI 2: f32 out + bias
template <int EPI>
__global__ __launch_bounds__(256, 2) void gemm_bt(
    const u16* __restrict__ A, const u16* __restrict__ B, void* __restrict__ Cv,
    const float* __restrict__ bias, int K, int lda, int ldb, int ldc,
    long sA, long sB, long sC, float scale)
{
    __shared__ u16 lA[128 * 32];
    __shared__ u16 lB[128 * 32];
    const int tid = threadIdx.x;
    const int lane = tid & 63;
    const int wid = tid >> 6;
    const int wr = wid >> 1, wc = wid & 1;
    const int z = blockIdx.z;
    A += (size_t)z * sA;
    B += (size_t)z * sB;
    int bx, by;
    xcd_map(bx, by);
    const int m0 = by * 128;
    const int n0 = bx * 128;

    f32x4 acc[4][4];
#pragma unroll
    for (int i = 0; i < 4; i++)
#pragma unroll
        for (int j = 0; j < 4; j++)
#pragma unroll
            for (int r = 0; r < 4; r++) acc[i][j][r] = 0.0f;

    const int ar = lane & 15;
    const int ak = (lane >> 4) * 8;
    const int srow = tid >> 2;
    const int scol = (tid & 3) * 8;
    const u16* ga = A + (size_t)(m0 + srow) * lda + scol;
    const u16* gb = B + (size_t)(n0 + srow) * ldb + scol;

    for (int k0 = 0; k0 < K; k0 += 32) {
        gld16(ga + k0, &lA[tid * 8]);
        gld16(ga + k0 + (size_t)64 * lda, &lA[2048 + tid * 8]);
        gld16(gb + k0, &lB[tid * 8]);
        gld16(gb + k0 + (size_t)64 * ldb, &lB[2048 + tid * 8]);
        __syncthreads();
        bf16x8 afr[4], bfr[4];
#pragma unroll
        for (int mi = 0; mi < 4; mi++)
            afr[mi] = *(const bf16x8*)&lA[(wr * 64 + mi * 16 + ar) * 32 + ak];
#pragma unroll
        for (int ni = 0; ni < 4; ni++)
            bfr[ni] = *(const bf16x8*)&lB[(wc * 64 + ni * 16 + ar) * 32 + ak];
#pragma unroll
        for (int mi = 0; mi < 4; mi++)
#pragma unroll
            for (int ni = 0; ni < 4; ni++)
                acc[mi][ni] = __builtin_amdgcn_mfma_f32_16x16x32_bf16(
                    afr[mi], bfr[ni], acc[mi][ni], 0, 0, 0);
        __syncthreads();
    }

    const int rr = (lane >> 4) * 4;
    const int cc = lane & 15;
#pragma unroll
    for (int mi = 0; mi < 4; mi++) {
#pragma unroll
        for (int ni = 0; ni < 4; ni++) {
            const int col = n0 + wc * 64 + ni * 16 + cc;
            const int rowb = m0 + wr * 64 + mi * 16 + rr;
            if constexpr (EPI == 0) {
                u16* C = (u16*)Cv + (size_t)z * sC;
                const float bv = bias[col];
#pragma unroll
                for (int r = 0; r < 4; r++)
                    C[(size_t)(rowb + r) * ldc + col] = f2bf(acc[mi][ni][r] + bv);
            } else if constexpr (EPI == 1) {
                u16* C = (u16*)Cv + (size_t)z * sC;
#pragma unroll
                for (int r = 0; r < 4; r++)
                    C[(size_t)(rowb + r) * ldc + col] = f2bf(acc[mi][ni][r] * scale);
            } else {
                float* C = (float*)Cv + (size_t)z * sC;
                const float bv = bias[col];
#pragma unroll
                for (int r = 0; r < 4; r++)
                    C[(size_t)(rowb + r) * ldc + col] = acc[mi][ni][r] + bv;
            }
        }
    }
}

// ---------------- scores GEMM + fused per-128-tile softmax ----------------
__global__ __launch_bounds__(256, 2) void gemm_scores(
    const u16* __restrict__ Q, const u16* __restrict__ Kmat, u16* __restrict__ W,
    int K, int lda, int ldb, int ldc, long sQ, long sK, long sW)
{
    __shared__ u16 lA[128 * 32];
    __shared__ u16 lB[128 * 32];
    const int tid = threadIdx.x;
    const int lane = tid & 63;
    const int wid = tid >> 6;
    const int z = blockIdx.z;
    const u16* Aq = Q + (size_t)z * sQ;
    const u16* Bk = Kmat + (size_t)z * sK;
    int bx, by;
    xcd_map(bx, by);
    const int m0 = by * 128;
    const int n0 = bx * 128;

    f32x4 acc[2][8];
#pragma unroll
    for (int i = 0; i < 2; i++)
#pragma unroll
        for (int j = 0; j < 8; j++)
#pragma unroll
            for (int r = 0; r < 4; r++) acc[i][j][r] = 0.0f;

    const int ar = lane & 15;
    const int ak = (lane >> 4) * 8;
    const int srow = tid >> 2;
    const int scol = (tid & 3) * 8;
    const u16* ga = Aq + (size_t)(m0 + srow) * lda + scol;
    const u16* gb = Bk + (size_t)(n0 + srow) * ldb + scol;

    for (int k0 = 0; k0 < K; k0 += 32) {
        gld16(ga + k0, &lA[tid * 8]);
        gld16(ga + k0 + (size_t)64 * lda, &lA[2048 + tid * 8]);
        gld16(gb + k0, &lB[tid * 8]);
        gld16(gb + k0 + (size_t)64 * ldb, &lB[2048 + tid * 8]);
        __syncthreads();
        bf16x8 afr[2], bfr[8];
#pragma unroll
        for (int mi = 0; mi < 2; mi++)
            afr[mi] = *(const bf16x8*)&lA[(wid * 32 + mi * 16 + ar) * 32 + ak];
#pragma unroll
        for (int ni = 0; ni < 8; ni++)
            bfr[ni] = *(const bf16x8*)&lB[(ni * 16 + ar) * 32 + ak];
#pragma unroll
        for (int mi = 0; mi < 2; mi++)
#pragma unroll
            for (int ni = 0; ni < 8; ni++)
                acc[mi][ni] = __builtin_amdgcn_mfma_f32_16x16x32_bf16(
                    afr[mi], bfr[ni], acc[mi][ni], 0, 0, 0);
        __syncthreads();
    }

    const float SL = 0.03125f * 1.44269504088896341f;  // (1/sqrt(D)) * log2(e)
    const int g4 = (lane >> 4) * 4;
    const int cc = lane & 15;
    u16* Wp = W + (size_t)z * sW;
#pragma unroll
    for (int mi = 0; mi < 2; mi++) {
#pragma unroll
        for (int r = 0; r < 4; r++) {
            float m = acc[mi][0][r];
#pragma unroll
            for (int ni = 1; ni < 8; ni++) m = fmaxf(m, acc[mi][ni][r]);
            m = fmaxf(m, __shfl_xor(m, 1));
            m = fmaxf(m, __shfl_xor(m, 2));
            m = fmaxf(m, __shfl_xor(m, 4));
            m = fmaxf(m, __shfl_xor(m, 8));
            float e[8], s = 0.0f;
#pragma unroll
            for (int ni = 0; ni < 8; ni++) {
                e[ni] = exp2f((acc[mi][ni][r] - m) * SL);
                s += e[ni];
            }
            s += __shfl_xor(s, 1);
            s += __shfl_xor(s, 2);
            s += __shfl_xor(s, 4);
            s += __shfl_xor(s, 8);
            const float inv = 1.0f / s;
            const int row = m0 + wid * 32 + mi * 16 + g4 + r;
#pragma unroll
            for (int ni = 0; ni < 8; ni++)
                Wp[(size_t)row * ldc + n0 + ni * 16 + cc] = f2bf(e[ni] * inv);
        }
    }
}

// ---------------- launch ----------------
extern "C" void kernel_launch(void* const* d_in, const int* in_sizes, int n_in,
                              void* d_out, int out_size, void* d_ws, size_t ws_size,
                              hipStream_t stream)
{
    const float* X  = (const float*)d_in[0];
    const float* Wq = (const float*)d_in[1];
    const float* bq = (const float*)d_in[2];
    const float* Wk = (const float*)d_in[3];
    const float* bk = (const float*)d_in[4];
    const float* Wv = (const float*)d_in[5];
    const float* bv = (const float*)d_in[6];
    const float* Wo = (const float*)d_in[7];
    const float* bo = (const float*)d_in[8];
    float* OUT = (float*)d_out;

    u16* ws = (u16*)d_ws;
    const size_t NTOK = (size_t)B_ * S_;     // 8192
    const size_t XSZ = NTOK * D_;            // 8.39M elems
    u16* Xb   = ws;                          // [8192,1024] bf16 (reused as Ob)
    u16* QKVb = Xb + XSZ;                    // [8192,3072] bf16
    u16* Vt   = QKVb + NTOK * (size_t)(3 * D_);  // [B][1024][4096]
    u16* Wqb  = Vt + XSZ;                    // [Wq;Wk;Wv;Wo] bf16, contiguous
    u16* Wsm  = Wqb + (size_t)4 * D_ * D_;   // [B][4096][4096] softmaxed weights
    float* bqkv = (float*)(Wsm + (size_t)B_ * S_ * S_);  // [3072] f32
    u16* Ob   = Xb;                          // alias: X dead after QKV proj

    u16* Qp = QKVb;
    u16* Kp = QKVb + D_;
    u16* Vp = QKVb + 2 * D_;
    const int ldqkv = 3 * D_;

    cast_kernel<<<dim3(2048), dim3(256), 0, stream>>>(X, Xb, (int)(XSZ / 8));
    cast4_kernel<<<dim3(512, 4), dim3(256), 0, stream>>>(Wq, Wk, Wv, Wo, Wqb,
                                                         (int)((size_t)D_ * D_ / 8));
    concat_bias<<<dim3(12), dim3(256), 0, stream>>>(bq, bk, bv, bqkv);

    // Fused QKV projection: [8192,1024] x [3072,1024]^T -> [8192,3072]
    gemm_bt<0><<<dim3(3 * D_ / 128, NTOK / 128, 1), 256, 0, stream>>>(
        Xb, Wqb, QKVb, bqkv, D_, D_, D_, ldqkv, 0, 0, 0, 1.0f);

    transpose_v<<<dim3(D_ / 64, S_ / 64, B_), 256, 0, stream>>>(Vp, Vt, ldqkv);

    gemm_scores<<<dim3(S_ / 128, S_ / 128, B_), 256, 0, stream>>>(
        Qp, Kp, Wsm, D_, ldqkv, ldqkv, S_,
        (long)S_ * ldqkv, (long)S_ * ldqkv, (long)S_ * S_);

    gemm_bt<1><<<dim3(D_ / 128, S_ / 128, B_), 256, 0, stream>>>(
        Wsm, Vt, Ob, nullptr, S_, S_, S_, D_,
        (long)S_ * S_, (long)D_ * S_, (long)S_ * D_, 1.0f / (32.0f + 1e-6f));

    gemm_bt<2><<<dim3(D_ / 128, NTOK / 128, 1), 256, 0, stream>>>(
        Ob, Wqb + (size_t)3 * D_ * D_, OUT, bo, D_, D_, D_, D_, 0, 0, 0, 1.0f);
}